// Round 13
// baseline (154.148 us; speedup 1.0000x reference)
//
#include <hip/hip_runtime.h>
#include <hip/hip_bf16.h>

#define D 128
#define RCH 128                   // rows per chunk
#define NCH 782                   // ceil(100000/128); rows 100000..100095 empty
#define NCHP 1024                 // NCH padded for 4-chunks-per-thread scan
#define NB_S 500                  // scatter blocks
#define CH_S 3200                 // edges per scatter block (500*3200 = 1.6M)
#define OS2 800                   // offs2 row stride in ints (>= NCH+1)
#define CAP 3072                  // fixed record slots per chunk (lambda=2048, 22 sigma)
#define PB 128                    // weight-prep blocks
#define GB64 1563                 // gemm0 64-row blocks

typedef __attribute__((ext_vector_type(8))) short short8v;
typedef __attribute__((ext_vector_type(4))) float float4v;

__device__ inline ushort f2bf(float f) {
    __hip_bfloat16 h = __float2bfloat16(f);
    return __builtin_bit_cast(ushort, h);
}
__device__ inline float bf2f(ushort u) {
    return __builtin_bit_cast(float, (uint)u << 16);
}
__device__ inline ushort relu_bf(ushort u) { return (u & 0x8000u) ? (ushort)0 : u; }

// Stage Wt (128x128 bf16, 32 KB) into LDS with XOR swizzle (G4).
__device__ inline void stage_wt_lds(char* smem, const ushort* __restrict__ Wt,
                                    int tid) {
#pragma unroll
    for (int i = 0; i < 8; ++i) {
        const int L = tid * 128 + i * 16;
        const int row = L >> 8;
        const int off = L & 255;
        *(short8v*)(smem + row * 256 + (off ^ ((row & 7) << 4))) =
            *(const short8v*)((const char*)Wt + L);
    }
}

// ---------------------------------------------------------------------------
// K0: weight transpose+cast (tiny).
// ---------------------------------------------------------------------------
__global__ __launch_bounds__(256) void k0_prep(const float* __restrict__ W,
                                               const float* __restrict__ Wres,
                                               ushort* __restrict__ Wt,
                                               ushort* __restrict__ Wtres) {
    const int flat = blockIdx.x * 256 + threadIdx.x;   // 0..32767
    const float* src = (flat < 16384) ? W : Wres;
    ushort* dst = (flat < 16384) ? Wt : Wtres;
    const int f = flat & 16383;
    const int k = f >> 7, c = f & 127;
    dst[c * D + k] = f2bf(src[f]);
}

// ---------------------------------------------------------------------------
// KA: scatter (blocks [0,NB_S), latency-bound) || gemm0 (BW-bound).
// Round-9-validated pairing: non-SpMM pipeline 78 -> 62us.
// ---------------------------------------------------------------------------
__global__ __launch_bounds__(256) void kA_scatter_gemm(
    const float* __restrict__ ev, const int* __restrict__ er,
    const int* __restrict__ ec, int* __restrict__ offs2,
    int2* __restrict__ tmp, int E,
    const float* __restrict__ X, const ushort* __restrict__ Wt,
    const float* __restrict__ bias, ushort* __restrict__ hb, int N) {
    __shared__ char smem[32768];   // scatter: h+sscan; gemm: swizzled Wt

    if (blockIdx.x < NB_S) {
        int* h = (int*)smem;                    // NCHP ints (4 KB)
        int* sscan = (int*)(smem + 4 * NCHP);   // 256 ints (1 KB)
        const int b = blockIdx.x;
        const int t = threadIdx.x;
        const int start = b * CH_S;
        const int end = min(E, start + CH_S);
        const int nfull = (end - start) & ~3;

        for (int k = t; k < NCHP; k += 256) h[k] = 0;
        __syncthreads();

        // pass 1: histogram own edges by chunk (int4 loads)
        for (int o = 4 * t; o < nfull; o += 1024) {
            const int4 r4 = *(const int4*)(er + start + o);
            atomicAdd(&h[r4.x >> 7], 1);
            atomicAdd(&h[r4.y >> 7], 1);
            atomicAdd(&h[r4.z >> 7], 1);
            atomicAdd(&h[r4.w >> 7], 1);
        }
        for (int o = nfull + t; o < end - start; o += 256)
            atomicAdd(&h[er[start + o] >> 7], 1);
        __syncthreads();

        // scan: thread t owns chunks [4t, 4t+4)
        const int a0 = h[4 * t], a1 = h[4 * t + 1];
        const int a2 = h[4 * t + 2], a3 = h[4 * t + 3];
        const int tsum = a0 + a1 + a2 + a3;
        sscan[t] = tsum;
        __syncthreads();
        for (int o = 1; o < 256; o <<= 1) {
            const int a = (t >= o) ? sscan[t - o] : 0;
            __syncthreads();
            sscan[t] += a;
            __syncthreads();
        }
        const int ex = start + sscan[t] - tsum;   // absolute, block-private
        const int c0 = 4 * t;
        h[c0]     = ex;
        h[c0 + 1] = ex + a0;
        h[c0 + 2] = ex + a0 + a1;
        h[c0 + 3] = ex + a0 + a1 + a2;
        int* od = offs2 + (long)b * OS2;
#pragma unroll
        for (int i = 0; i < 4; ++i)
            if (c0 + i <= NCH) od[c0 + i] = h[c0 + i];
        __syncthreads();

        // pass 2: scatter into private region, grouped by chunk
        for (int o = 4 * t; o < nfull; o += 1024) {
            const int4 r4 = *(const int4*)(er + start + o);
            const int4 c4 = *(const int4*)(ec + start + o);
            const float4 v4 = *(const float4*)(ev + start + o);
            const int p0 = atomicAdd(&h[r4.x >> 7], 1);
            const int p1 = atomicAdd(&h[r4.y >> 7], 1);
            const int p2 = atomicAdd(&h[r4.z >> 7], 1);
            const int p3 = atomicAdd(&h[r4.w >> 7], 1);
            tmp[p0] = make_int2((c4.x << 7) | (r4.x & 127), __float_as_int(v4.x));
            tmp[p1] = make_int2((c4.y << 7) | (r4.y & 127), __float_as_int(v4.y));
            tmp[p2] = make_int2((c4.z << 7) | (r4.z & 127), __float_as_int(v4.z));
            tmp[p3] = make_int2((c4.w << 7) | (r4.w & 127), __float_as_int(v4.w));
        }
        for (int o = nfull + t; o < end - start; o += 256) {
            const int e = start + o;
            const int r = er[e];
            const int pos = atomicAdd(&h[r >> 7], 1);
            tmp[pos] = make_int2((ec[e] << 7) | (r & 127), __float_as_int(ev[e]));
        }
        return;
    }

    // ---- gemm0: h = x@W + b, 64 rows/block, Wt in swizzled LDS ----
    const int g = blockIdx.x - NB_S;
    const int t = threadIdx.x;
    const int lane = t & 63;
    const int w = t >> 6;
    const int l16 = lane & 15;
    const int lk = lane >> 4;
    const long wRow = (long)g * 64 + w * 16;

    short8v afrag[4];
    {
        long r = wRow + l16;
        if (r >= N) r = N - 1;
        const float* xp = X + r * D + lk * 8;
#pragma unroll
        for (int ks = 0; ks < 4; ++ks) {
            const float4 u0 = *(const float4*)(xp + ks * 32);
            const float4 u1 = *(const float4*)(xp + ks * 32 + 4);
            float f[8] = {u0.x, u0.y, u0.z, u0.w, u1.x, u1.y, u1.z, u1.w};
            short8v a;
#pragma unroll
            for (int i = 0; i < 8; ++i) a[i] = (short)f2bf(f[i]);
            afrag[ks] = a;
        }
    }

    stage_wt_lds(smem, Wt, t);
    __syncthreads();

    float4v acc[8];
#pragma unroll
    for (int q = 0; q < 8; ++q) acc[q] = (float4v)(0.0f);

    const int swz = (l16 & 7) << 4;
#pragma unroll
    for (int ks = 0; ks < 4; ++ks) {
#pragma unroll
        for (int q = 0; q < 8; ++q) {
            const int row = q * 16 + l16;
            const short8v bfrag = *(const short8v*)(
                smem + row * 256 + ((ks * 64 + lk * 16) ^ swz));
            acc[q] = __builtin_amdgcn_mfma_f32_16x16x32_bf16(afrag[ks], bfrag,
                                                             acc[q], 0, 0, 0);
        }
    }

#pragma unroll
    for (int q = 0; q < 8; ++q) {
        const int col = q * 16 + l16;
        const float bb = bias[col];
#pragma unroll
        for (int i = 0; i < 4; ++i) {
            const long row = wRow + lk * 4 + i;
            if (row < N) hb[row * D + col] = f2bf(acc[q][i] + bb);
        }
    }
}

// ---------------------------------------------------------------------------
// KB: per-chunk gather + counting sort -> recs/rowptr.
// ---------------------------------------------------------------------------
__global__ __launch_bounds__(256) void kB_sort(const int2* __restrict__ tmp,
                                               const int* __restrict__ offs2,
                                               int2* __restrict__ recs,
                                               int* __restrict__ rowptr) {
    __shared__ int2 buf[CAP];    // 24 KB
    __shared__ int sb[256];
    __shared__ int hcnt[RCH];
    __shared__ int sc[RCH];
    __shared__ int cur[RCH];
    const int c = blockIdx.x;
    const int t = threadIdx.x;
    const int s = c * CAP;

    int segA = 0, cbA = 0, segB = 0, cbB = 0;
    if (t < NB_S / 2) {   // 250 active threads, 2 scatter blocks each
        const int* oA = offs2 + (long)(2 * t) * OS2;
        const int* oB = offs2 + (long)(2 * t + 1) * OS2;
        segA = oA[c]; cbA = oA[c + 1] - segA;
        segB = oB[c]; cbB = oB[c + 1] - segB;
    }
    const int cb = cbA + cbB;

    sb[t] = cb;
    __syncthreads();
    for (int o = 1; o < 256; o <<= 1) {
        const int a = (t >= o) ? sb[t - o] : 0;
        __syncthreads();
        sb[t] += a;
        __syncthreads();
    }
    const int base = sb[t] - cb;
    const int cnt = min(sb[255], CAP);

    if (t < RCH) hcnt[t] = 0;
    __syncthreads();

    for (int i = 0; i < cbA; ++i) {
        const int p = base + i;
        if (p >= CAP) break;
        const int2 r = tmp[segA + i];
        buf[p] = r;
        atomicAdd(&hcnt[r.x & 127], 1);
    }
    for (int i = 0; i < cbB; ++i) {
        const int p = base + cbA + i;
        if (p >= CAP) break;
        const int2 r = tmp[segB + i];
        buf[p] = r;
        atomicAdd(&hcnt[r.x & 127], 1);
    }
    __syncthreads();

    if (t < RCH) sc[t] = hcnt[t];
    __syncthreads();
    for (int o = 1; o < RCH; o <<= 1) {
        const int a = (t < RCH && t >= o) ? sc[t - o] : 0;
        __syncthreads();
        if (t < RCH) sc[t] += a;
        __syncthreads();
    }
    if (t < RCH) {
        const int ex = s + sc[t] - hcnt[t];
        cur[t] = ex;
        rowptr[c * (RCH + 1) + t] = ex;
    }
    if (t == 0) rowptr[c * (RCH + 1) + RCH] = s + cnt;
    __syncthreads();

    for (int k = t; k < cnt; k += 256) {
        const int2 r = buf[k];
        const int pos = atomicAdd(&cur[r.x & 127], 1);
        // byte offset: (col) * 256 = ((r.x >> 7) << 8)
        recs[pos] = make_int2((r.x >> 7) << 8, r.y);
    }
}

// ---------------------------------------------------------------------------
// K56 v4: round-9 v1 (best: 16-row blocks, static pair/wave, 6250 blocks ->
// fine-grained drain; v3's 64-row blocks = coarse drain tail, regressed)
// MINUS the Wtres LDS staging: phase 3 reads bfrag direct from L2-resident
// Wtres (v3-proven pattern; 32KB stays hot per XCD). Deletes 200 MB of L2
// staging reads + per-block staging burst; LDS 36KB -> 4KB.
// ---------------------------------------------------------------------------
#define GFMA2(accv, rr, gg)                                                   \
    accv.x = fmaf(__int_as_float((rr).y), bf2f((ushort)((gg)&0xffffu)), accv.x);\
    accv.y = fmaf(__int_as_float((rr).y), bf2f((ushort)((gg) >> 16)), accv.y);

__device__ inline void drain_row(const int2* __restrict__ recs,
                                 const char* __restrict__ hpc,
                                 int& j, int e, float2& acc) {
    for (; j + 8 <= e; j += 8) {
        const int2 r0 = recs[j],     r1 = recs[j + 1];
        const int2 r2 = recs[j + 2], r3 = recs[j + 3];
        const int2 r4 = recs[j + 4], r5 = recs[j + 5];
        const int2 r6 = recs[j + 6], r7 = recs[j + 7];
        const uint g0 = *(const uint*)(hpc + (uint)r0.x);
        const uint g1 = *(const uint*)(hpc + (uint)r1.x);
        const uint g2 = *(const uint*)(hpc + (uint)r2.x);
        const uint g3 = *(const uint*)(hpc + (uint)r3.x);
        const uint g4 = *(const uint*)(hpc + (uint)r4.x);
        const uint g5 = *(const uint*)(hpc + (uint)r5.x);
        const uint g6 = *(const uint*)(hpc + (uint)r6.x);
        const uint g7 = *(const uint*)(hpc + (uint)r7.x);
        GFMA2(acc, r0, g0) GFMA2(acc, r1, g1) GFMA2(acc, r2, g2) GFMA2(acc, r3, g3)
        GFMA2(acc, r4, g4) GFMA2(acc, r5, g5) GFMA2(acc, r6, g6) GFMA2(acc, r7, g7)
    }
    for (; j + 2 <= e; j += 2) {
        const int2 r0 = recs[j], r1 = recs[j + 1];
        const uint g0 = *(const uint*)(hpc + (uint)r0.x);
        const uint g1 = *(const uint*)(hpc + (uint)r1.x);
        GFMA2(acc, r0, g0) GFMA2(acc, r1, g1)
    }
    if (j < e) {
        const int2 r0 = recs[j];
        const uint g0 = *(const uint*)(hpc + (uint)r0.x);
        GFMA2(acc, r0, g0)
    }
}

__global__ __launch_bounds__(512, 8) void k56_spmm_gemm1(
    const ushort* __restrict__ hb, const int2* __restrict__ recs,
    const int* __restrict__ rowptr, const ushort* __restrict__ Wtres,
    const float* __restrict__ bres, float* __restrict__ Y, int N) {
    __shared__ char agg[4096];    // 16x128 bf16 relu(agg), swizzled
    const int t = threadIdx.x;
    const int w = t >> 6;
    const int lane = t & 63;

    // ---- phase 1: gather, 2 rows per wave (round-5 k5 body) ----
    const int rowA = blockIdx.x * 16 + w * 2;   // grid exact: max 99998
    const int c = rowA >> 7;
    const int tr = rowA & 127;                  // even, <= 126
    int rp = 0;
    if (lane < 3) rp = rowptr[c * (RCH + 1) + tr + lane];
    const int sA = __shfl(rp, 0);
    const int eA = __shfl(rp, 1);
    const int sB = eA;
    const int eB = __shfl(rp, 2);

    const char* hpc = (const char*)hb + lane * 4;
    float2 accA = make_float2(0.f, 0.f);
    float2 accB = make_float2(0.f, 0.f);

    int jA = sA, jB = sB;
    while (jA + 8 <= eA && jB + 8 <= eB) {
        const int2 a0 = recs[jA],     a1 = recs[jA + 1];
        const int2 a2 = recs[jA + 2], a3 = recs[jA + 3];
        const int2 a4 = recs[jA + 4], a5 = recs[jA + 5];
        const int2 a6 = recs[jA + 6], a7 = recs[jA + 7];
        const int2 b0 = recs[jB],     b1 = recs[jB + 1];
        const int2 b2 = recs[jB + 2], b3 = recs[jB + 3];
        const int2 b4 = recs[jB + 4], b5 = recs[jB + 5];
        const int2 b6 = recs[jB + 6], b7 = recs[jB + 7];
        const uint ga0 = *(const uint*)(hpc + (uint)a0.x);
        const uint ga1 = *(const uint*)(hpc + (uint)a1.x);
        const uint ga2 = *(const uint*)(hpc + (uint)a2.x);
        const uint ga3 = *(const uint*)(hpc + (uint)a3.x);
        const uint ga4 = *(const uint*)(hpc + (uint)a4.x);
        const uint ga5 = *(const uint*)(hpc + (uint)a5.x);
        const uint ga6 = *(const uint*)(hpc + (uint)a6.x);
        const uint ga7 = *(const uint*)(hpc + (uint)a7.x);
        const uint gb0 = *(const uint*)(hpc + (uint)b0.x);
        const uint gb1 = *(const uint*)(hpc + (uint)b1.x);
        const uint gb2 = *(const uint*)(hpc + (uint)b2.x);
        const uint gb3 = *(const uint*)(hpc + (uint)b3.x);
        const uint gb4 = *(const uint*)(hpc + (uint)b4.x);
        const uint gb5 = *(const uint*)(hpc + (uint)b5.x);
        const uint gb6 = *(const uint*)(hpc + (uint)b6.x);
        const uint gb7 = *(const uint*)(hpc + (uint)b7.x);
        GFMA2(accA, a0, ga0) GFMA2(accA, a1, ga1) GFMA2(accA, a2, ga2) GFMA2(accA, a3, ga3)
        GFMA2(accA, a4, ga4) GFMA2(accA, a5, ga5) GFMA2(accA, a6, ga6) GFMA2(accA, a7, ga7)
        GFMA2(accB, b0, gb0) GFMA2(accB, b1, gb1) GFMA2(accB, b2, gb2) GFMA2(accB, b3, gb3)
        GFMA2(accB, b4, gb4) GFMA2(accB, b5, gb5) GFMA2(accB, b6, gb6) GFMA2(accB, b7, gb7)
        jA += 8;
        jB += 8;
    }
    drain_row(recs, hpc, jA, eA, accA);
    drain_row(recs, hpc, jB, eB, accB);

    // ---- phase 2: relu + bf16 pack -> swizzled LDS tile ----
    {
        const uint pA = (uint)relu_bf(f2bf(accA.x)) |
                        ((uint)relu_bf(f2bf(accA.y)) << 16);
        const uint pB = (uint)relu_bf(f2bf(accB.x)) |
                        ((uint)relu_bf(f2bf(accB.y)) << 16);
        const int rA = 2 * w, rB = 2 * w + 1;
        *(uint*)(agg + rA * 256 + ((lane * 4) ^ ((rA & 7) << 4))) = pA;
        *(uint*)(agg + rB * 256 + ((lane * 4) ^ ((rB & 7) << 4))) = pB;
    }
    __syncthreads();

    // ---- phase 3: out = relu(agg) + relu(agg) @ Wres + bres ----
    // bfrag direct from L2-resident Wtres (v3-proven); afrag from agg LDS.
    const int l16 = lane & 15;
    const int lk = lane >> 4;
    const int ct = w;                 // col tile 0..7
    const int aswz = (l16 & 7) << 4;

    float4v acc = (float4v)(0.0f);
#pragma unroll
    for (int ks = 0; ks < 4; ++ks) {
        const short8v af = *(const short8v*)(
            agg + l16 * 256 + ((ks * 64 + lk * 16) ^ aswz));
        const short8v bf = *(const short8v*)(
            Wtres + (long)(ct * 16 + l16) * D + ks * 32 + lk * 8);
        acc = __builtin_amdgcn_mfma_f32_16x16x32_bf16(af, bf, acc, 0, 0, 0);
    }

    const int col = ct * 16 + l16;
    const float bb = bres[col];
#pragma unroll
    for (int i = 0; i < 4; ++i) {
        const int rl = lk * 4 + i;
        const ushort au = *(const ushort*)(
            agg + rl * 256 + ((col * 2) ^ ((rl & 7) << 4)));
        const long grow = (long)blockIdx.x * 16 + rl;
        Y[grow * D + col] = bf2f(au) + acc[i] + bb;
    }
}

extern "C" void kernel_launch(void* const* d_in, const int* in_sizes, int n_in,
                              void* d_out, int out_size, void* d_ws, size_t ws_size,
                              hipStream_t stream) {
    const float* x    = (const float*)d_in[0];
    const float* W    = (const float*)d_in[1];
    const float* b    = (const float*)d_in[2];
    const float* Wres = (const float*)d_in[3];
    const float* bres = (const float*)d_in[4];
    const float* ev   = (const float*)d_in[5];
    const int*   er   = (const int*)d_in[6];
    const int*   ec   = (const int*)d_in[7];

    float* out = (float*)d_out;

    const int n = in_sizes[0] / D;   // 100000
    const int e = in_sizes[5];       // 1600000

    // ---- workspace layout ----
    char* ws = (char*)d_ws;
    size_t off_b = 0;
    auto alloc = [&](size_t bytes) {
        void* p = ws + off_b;
        off_b += (bytes + 511) & ~size_t(511);
        return p;
    };
    ushort* hb     = (ushort*)alloc((size_t)n * D * sizeof(ushort));        // 25.6 MB
    int2*   recs   = (int2*)alloc((size_t)NCH * CAP * sizeof(int2));        // 19.2 MB
    int*    rowptr = (int*)alloc((size_t)NCH * (RCH + 1) * sizeof(int));    // 403 KB
    ushort* Wt     = (ushort*)alloc((size_t)D * D * sizeof(ushort));
    ushort* Wtres  = (ushort*)alloc((size_t)D * D * sizeof(ushort));
    int2*   tmp    = (int2*)alloc((size_t)NB_S * CH_S * sizeof(int2));      // 12.8 MB
    int*    offs2  = (int*)alloc((size_t)NB_S * OS2 * sizeof(int));         // 1.6 MB
    (void)ws_size;

    // K0: weight transpose+cast
    k0_prep<<<PB, 256, 0, stream>>>(W, Wres, Wt, Wtres);

    // KA: scatter (latency-bound) || gemm0 h = x@W+b (BW-bound)
    kA_scatter_gemm<<<NB_S + GB64, 256, 0, stream>>>(ev, er, ec, offs2, tmp, e,
                                                     x, Wt, b, hb, n);

    // KB: per-chunk gather+sort -> recs/rowptr
    kB_sort<<<NCH, 256, 0, stream>>>(tmp, offs2, recs, rowptr);

    // K56 v4: fused gather-aggregate + residual GEMM (staging-free phase 3)
    k56_spmm_gemm1<<<(n + 15) / 16, 512, 0, stream>>>(hb, recs, rowptr,
                                                      Wtres, bres, out, n);
}

// Round 14
// 142.764 us; speedup vs baseline: 1.0797x; 1.0797x over previous
//
#include <hip/hip_runtime.h>
#include <hip/hip_bf16.h>

#define D 128
#define RCH 128                   // rows per chunk
#define NCH 782                   // ceil(100000/128); rows 100000..100095 empty
#define NCHP 1024                 // NCH padded for 4-chunks-per-thread scan
#define NB_S 500                  // scatter blocks
#define CH_S 3200                 // edges per scatter block (500*3200 = 1.6M)
#define OS2 800                   // offs2 row stride in ints (>= NCH+1)
#define CAP 3072                  // fixed record slots per chunk (lambda=2048, 22 sigma)
#define PB 128                    // weight-prep blocks
#define GB64 1563                 // gemm0 64-row blocks

typedef __attribute__((ext_vector_type(8))) short short8v;
typedef __attribute__((ext_vector_type(4))) float float4v;

__device__ inline ushort f2bf(float f) {
    __hip_bfloat16 h = __float2bfloat16(f);
    return __builtin_bit_cast(ushort, h);
}
__device__ inline float bf2f(ushort u) {
    return __builtin_bit_cast(float, (uint)u << 16);
}
__device__ inline ushort relu_bf(ushort u) { return (u & 0x8000u) ? (ushort)0 : u; }

// Stage Wt (128x128 bf16, 32 KB) into LDS with XOR swizzle (G4).
// 256-thread version: 128 B per thread.
__device__ inline void stage_wt_lds(char* smem, const ushort* __restrict__ Wt,
                                    int tid) {
#pragma unroll
    for (int i = 0; i < 8; ++i) {
        const int L = tid * 128 + i * 16;
        const int row = L >> 8;
        const int off = L & 255;
        *(short8v*)(smem + row * 256 + (off ^ ((row & 7) << 4))) =
            *(const short8v*)((const char*)Wt + L);
    }
}

// 512-thread version: 64 B per thread.
__device__ inline void stage_wt_lds512(char* smem, const ushort* __restrict__ Wt,
                                       int tid) {
#pragma unroll
    for (int i = 0; i < 4; ++i) {
        const int L = tid * 64 + i * 16;
        const int row = L >> 8;
        const int off = L & 255;
        *(short8v*)(smem + row * 256 + (off ^ ((row & 7) << 4))) =
            *(const short8v*)((const char*)Wt + L);
    }
}

// ---------------------------------------------------------------------------
// K0: weight transpose+cast (tiny; separate dispatch so kA's gemm can read
// prebuilt Wt without an intra-kernel prep->gemm race).
// ---------------------------------------------------------------------------
__global__ __launch_bounds__(256) void k0_prep(const float* __restrict__ W,
                                               const float* __restrict__ Wres,
                                               ushort* __restrict__ Wt,
                                               ushort* __restrict__ Wtres) {
    const int flat = blockIdx.x * 256 + threadIdx.x;   // 0..32767
    const float* src = (flat < 16384) ? W : Wres;
    ushort* dst = (flat < 16384) ? Wt : Wtres;
    const int f = flat & 16383;
    const int k = f >> 7, c = f & 127;
    dst[c * D + k] = f2bf(src[f]);
}

// ---------------------------------------------------------------------------
// KA: scatter (blocks [0,NB_S), latency-bound) || gemm0 (blocks
// [NB_S, NB_S+GB64), BW-bound). Round-9-validated pairing.
// ---------------------------------------------------------------------------
__global__ __launch_bounds__(256) void kA_scatter_gemm(
    const float* __restrict__ ev, const int* __restrict__ er,
    const int* __restrict__ ec, int* __restrict__ offs2,
    int2* __restrict__ tmp, int E,
    const float* __restrict__ X, const ushort* __restrict__ Wt,
    const float* __restrict__ bias, ushort* __restrict__ hb, int N) {
    __shared__ char smem[32768];   // scatter: h+sscan; gemm: swizzled Wt

    if (blockIdx.x < NB_S) {
        int* h = (int*)smem;                    // NCHP ints (4 KB)
        int* sscan = (int*)(smem + 4 * NCHP);   // 256 ints (1 KB)
        const int b = blockIdx.x;
        const int t = threadIdx.x;
        const int start = b * CH_S;
        const int end = min(E, start + CH_S);
        const int nfull = (end - start) & ~3;

        for (int k = t; k < NCHP; k += 256) h[k] = 0;
        __syncthreads();

        // pass 1: histogram own edges by chunk (int4 loads)
        for (int o = 4 * t; o < nfull; o += 1024) {
            const int4 r4 = *(const int4*)(er + start + o);
            atomicAdd(&h[r4.x >> 7], 1);
            atomicAdd(&h[r4.y >> 7], 1);
            atomicAdd(&h[r4.z >> 7], 1);
            atomicAdd(&h[r4.w >> 7], 1);
        }
        for (int o = nfull + t; o < end - start; o += 256)
            atomicAdd(&h[er[start + o] >> 7], 1);
        __syncthreads();

        // scan: thread t owns chunks [4t, 4t+4)
        const int a0 = h[4 * t], a1 = h[4 * t + 1];
        const int a2 = h[4 * t + 2], a3 = h[4 * t + 3];
        const int tsum = a0 + a1 + a2 + a3;
        sscan[t] = tsum;
        __syncthreads();
        for (int o = 1; o < 256; o <<= 1) {
            const int a = (t >= o) ? sscan[t - o] : 0;
            __syncthreads();
            sscan[t] += a;
            __syncthreads();
        }
        const int ex = start + sscan[t] - tsum;   // absolute, block-private
        const int c0 = 4 * t;
        h[c0]     = ex;
        h[c0 + 1] = ex + a0;
        h[c0 + 2] = ex + a0 + a1;
        h[c0 + 3] = ex + a0 + a1 + a2;
        int* od = offs2 + (long)b * OS2;
#pragma unroll
        for (int i = 0; i < 4; ++i)
            if (c0 + i <= NCH) od[c0 + i] = h[c0 + i];
        __syncthreads();

        // pass 2: scatter into private region, grouped by chunk
        for (int o = 4 * t; o < nfull; o += 1024) {
            const int4 r4 = *(const int4*)(er + start + o);
            const int4 c4 = *(const int4*)(ec + start + o);
            const float4 v4 = *(const float4*)(ev + start + o);
            const int p0 = atomicAdd(&h[r4.x >> 7], 1);
            const int p1 = atomicAdd(&h[r4.y >> 7], 1);
            const int p2 = atomicAdd(&h[r4.z >> 7], 1);
            const int p3 = atomicAdd(&h[r4.w >> 7], 1);
            tmp[p0] = make_int2((c4.x << 7) | (r4.x & 127), __float_as_int(v4.x));
            tmp[p1] = make_int2((c4.y << 7) | (r4.y & 127), __float_as_int(v4.y));
            tmp[p2] = make_int2((c4.z << 7) | (r4.z & 127), __float_as_int(v4.z));
            tmp[p3] = make_int2((c4.w << 7) | (r4.w & 127), __float_as_int(v4.w));
        }
        for (int o = nfull + t; o < end - start; o += 256) {
            const int e = start + o;
            const int r = er[e];
            const int pos = atomicAdd(&h[r >> 7], 1);
            tmp[pos] = make_int2((ec[e] << 7) | (r & 127), __float_as_int(ev[e]));
        }
        return;
    }

    // ---- gemm0: h = x@W + b, 64 rows/block, Wt in swizzled LDS ----
    const int g = blockIdx.x - NB_S;
    const int t = threadIdx.x;
    const int lane = t & 63;
    const int w = t >> 6;
    const int l16 = lane & 15;
    const int lk = lane >> 4;
    const long wRow = (long)g * 64 + w * 16;

    short8v afrag[4];
    {
        long r = wRow + l16;
        if (r >= N) r = N - 1;
        const float* xp = X + r * D + lk * 8;
#pragma unroll
        for (int ks = 0; ks < 4; ++ks) {
            const float4 u0 = *(const float4*)(xp + ks * 32);
            const float4 u1 = *(const float4*)(xp + ks * 32 + 4);
            float f[8] = {u0.x, u0.y, u0.z, u0.w, u1.x, u1.y, u1.z, u1.w};
            short8v a;
#pragma unroll
            for (int i = 0; i < 8; ++i) a[i] = (short)f2bf(f[i]);
            afrag[ks] = a;
        }
    }

    stage_wt_lds(smem, Wt, t);
    __syncthreads();

    float4v acc[8];
#pragma unroll
    for (int q = 0; q < 8; ++q) acc[q] = (float4v)(0.0f);

    const int swz = (l16 & 7) << 4;
#pragma unroll
    for (int ks = 0; ks < 4; ++ks) {
#pragma unroll
        for (int q = 0; q < 8; ++q) {
            const int row = q * 16 + l16;
            const short8v bfrag = *(const short8v*)(
                smem + row * 256 + ((ks * 64 + lk * 16) ^ swz));
            acc[q] = __builtin_amdgcn_mfma_f32_16x16x32_bf16(afrag[ks], bfrag,
                                                             acc[q], 0, 0, 0);
        }
    }

#pragma unroll
    for (int q = 0; q < 8; ++q) {
        const int col = q * 16 + l16;
        const float bb = bias[col];
#pragma unroll
        for (int i = 0; i < 4; ++i) {
            const long row = wRow + lk * 4 + i;
            if (row < N) hb[row * D + col] = f2bf(acc[q][i] + bb);
        }
    }
}

// ---------------------------------------------------------------------------
// KB: per-chunk gather + counting sort -> recs/rowptr.
// ---------------------------------------------------------------------------
__global__ __launch_bounds__(256) void kB_sort(const int2* __restrict__ tmp,
                                               const int* __restrict__ offs2,
                                               int2* __restrict__ recs,
                                               int* __restrict__ rowptr) {
    __shared__ int2 buf[CAP];    // 24 KB
    __shared__ int sb[256];
    __shared__ int hcnt[RCH];
    __shared__ int sc[RCH];
    __shared__ int cur[RCH];
    const int c = blockIdx.x;
    const int t = threadIdx.x;
    const int s = c * CAP;

    int segA = 0, cbA = 0, segB = 0, cbB = 0;
    if (t < NB_S / 2) {   // 250 active threads, 2 scatter blocks each
        const int* oA = offs2 + (long)(2 * t) * OS2;
        const int* oB = offs2 + (long)(2 * t + 1) * OS2;
        segA = oA[c]; cbA = oA[c + 1] - segA;
        segB = oB[c]; cbB = oB[c + 1] - segB;
    }
    const int cb = cbA + cbB;

    sb[t] = cb;
    __syncthreads();
    for (int o = 1; o < 256; o <<= 1) {
        const int a = (t >= o) ? sb[t - o] : 0;
        __syncthreads();
        sb[t] += a;
        __syncthreads();
    }
    const int base = sb[t] - cb;
    const int cnt = min(sb[255], CAP);

    if (t < RCH) hcnt[t] = 0;
    __syncthreads();

    for (int i = 0; i < cbA; ++i) {
        const int p = base + i;
        if (p >= CAP) break;
        const int2 r = tmp[segA + i];
        buf[p] = r;
        atomicAdd(&hcnt[r.x & 127], 1);
    }
    for (int i = 0; i < cbB; ++i) {
        const int p = base + cbA + i;
        if (p >= CAP) break;
        const int2 r = tmp[segB + i];
        buf[p] = r;
        atomicAdd(&hcnt[r.x & 127], 1);
    }
    __syncthreads();

    if (t < RCH) sc[t] = hcnt[t];
    __syncthreads();
    for (int o = 1; o < RCH; o <<= 1) {
        const int a = (t < RCH && t >= o) ? sc[t - o] : 0;
        __syncthreads();
        if (t < RCH) sc[t] += a;
        __syncthreads();
    }
    if (t < RCH) {
        const int ex = s + sc[t] - hcnt[t];
        cur[t] = ex;
        rowptr[c * (RCH + 1) + t] = ex;
    }
    if (t == 0) rowptr[c * (RCH + 1) + RCH] = s + cnt;
    __syncthreads();

    for (int k = t; k < cnt; k += 256) {
        const int2 r = buf[k];
        const int pos = atomicAdd(&cur[r.x & 127], 1);
        // byte offset: (col) * 256 = ((r.x >> 7) << 8)
        recs[pos] = make_int2((r.x >> 7) << 8, r.y);
    }
}

// ---------------------------------------------------------------------------
// K56 (round-9 v1, session best): fused SpMM + residual GEMM. 512-thread
// blocks own 16 rows: Wtres staged to LDS at block start (fully hidden
// under the gather — v4 proved deleting it EXPOSES L2 latency instead);
// phase 1 = dual-stream gather (2 rows/wave); phase 2 = relu->bf16 pack
// into 4KB swizzled LDS tile; barrier; phase 3 = 16x128 @ Wres MFMA +
// in-LDS residual. Alternatives all measured worse: v2 per-wave MFMA 91,
// v3 dynamic-queue 64-row 84.5, v4 staging-free 91.
// ---------------------------------------------------------------------------
#define GFMA2(accv, rr, gg)                                                   \
    accv.x = fmaf(__int_as_float((rr).y), bf2f((ushort)((gg)&0xffffu)), accv.x);\
    accv.y = fmaf(__int_as_float((rr).y), bf2f((ushort)((gg) >> 16)), accv.y);

__device__ inline void drain_row(const int2* __restrict__ recs,
                                 const char* __restrict__ hpc,
                                 int& j, int e, float2& acc) {
    for (; j + 8 <= e; j += 8) {
        const int2 r0 = recs[j],     r1 = recs[j + 1];
        const int2 r2 = recs[j + 2], r3 = recs[j + 3];
        const int2 r4 = recs[j + 4], r5 = recs[j + 5];
        const int2 r6 = recs[j + 6], r7 = recs[j + 7];
        const uint g0 = *(const uint*)(hpc + (uint)r0.x);
        const uint g1 = *(const uint*)(hpc + (uint)r1.x);
        const uint g2 = *(const uint*)(hpc + (uint)r2.x);
        const uint g3 = *(const uint*)(hpc + (uint)r3.x);
        const uint g4 = *(const uint*)(hpc + (uint)r4.x);
        const uint g5 = *(const uint*)(hpc + (uint)r5.x);
        const uint g6 = *(const uint*)(hpc + (uint)r6.x);
        const uint g7 = *(const uint*)(hpc + (uint)r7.x);
        GFMA2(acc, r0, g0) GFMA2(acc, r1, g1) GFMA2(acc, r2, g2) GFMA2(acc, r3, g3)
        GFMA2(acc, r4, g4) GFMA2(acc, r5, g5) GFMA2(acc, r6, g6) GFMA2(acc, r7, g7)
    }
    for (; j + 2 <= e; j += 2) {
        const int2 r0 = recs[j], r1 = recs[j + 1];
        const uint g0 = *(const uint*)(hpc + (uint)r0.x);
        const uint g1 = *(const uint*)(hpc + (uint)r1.x);
        GFMA2(acc, r0, g0) GFMA2(acc, r1, g1)
    }
    if (j < e) {
        const int2 r0 = recs[j];
        const uint g0 = *(const uint*)(hpc + (uint)r0.x);
        GFMA2(acc, r0, g0)
    }
}

__global__ __launch_bounds__(512, 8) void k56_spmm_gemm1(
    const ushort* __restrict__ hb, const int2* __restrict__ recs,
    const int* __restrict__ rowptr, const ushort* __restrict__ Wtres,
    const float* __restrict__ bres, float* __restrict__ Y, int N) {
    __shared__ char wsm[32768];   // swizzled Wtres
    __shared__ char agg[4096];    // 16x128 bf16 relu(agg), swizzled
    const int t = threadIdx.x;
    const int w = t >> 6;
    const int lane = t & 63;

    stage_wt_lds512(wsm, Wtres, t);

    // ---- phase 1: gather, 2 rows per wave (round-5 k5 body) ----
    const int rowA = blockIdx.x * 16 + w * 2;   // grid exact: max 99998
    const int c = rowA >> 7;
    const int tr = rowA & 127;                  // even, <= 126
    int rp = 0;
    if (lane < 3) rp = rowptr[c * (RCH + 1) + tr + lane];
    const int sA = __shfl(rp, 0);
    const int eA = __shfl(rp, 1);
    const int sB = eA;
    const int eB = __shfl(rp, 2);

    const char* hpc = (const char*)hb + lane * 4;
    float2 accA = make_float2(0.f, 0.f);
    float2 accB = make_float2(0.f, 0.f);

    int jA = sA, jB = sB;
    while (jA + 8 <= eA && jB + 8 <= eB) {
        const int2 a0 = recs[jA],     a1 = recs[jA + 1];
        const int2 a2 = recs[jA + 2], a3 = recs[jA + 3];
        const int2 a4 = recs[jA + 4], a5 = recs[jA + 5];
        const int2 a6 = recs[jA + 6], a7 = recs[jA + 7];
        const int2 b0 = recs[jB],     b1 = recs[jB + 1];
        const int2 b2 = recs[jB + 2], b3 = recs[jB + 3];
        const int2 b4 = recs[jB + 4], b5 = recs[jB + 5];
        const int2 b6 = recs[jB + 6], b7 = recs[jB + 7];
        const uint ga0 = *(const uint*)(hpc + (uint)a0.x);
        const uint ga1 = *(const uint*)(hpc + (uint)a1.x);
        const uint ga2 = *(const uint*)(hpc + (uint)a2.x);
        const uint ga3 = *(const uint*)(hpc + (uint)a3.x);
        const uint ga4 = *(const uint*)(hpc + (uint)a4.x);
        const uint ga5 = *(const uint*)(hpc + (uint)a5.x);
        const uint ga6 = *(const uint*)(hpc + (uint)a6.x);
        const uint ga7 = *(const uint*)(hpc + (uint)a7.x);
        const uint gb0 = *(const uint*)(hpc + (uint)b0.x);
        const uint gb1 = *(const uint*)(hpc + (uint)b1.x);
        const uint gb2 = *(const uint*)(hpc + (uint)b2.x);
        const uint gb3 = *(const uint*)(hpc + (uint)b3.x);
        const uint gb4 = *(const uint*)(hpc + (uint)b4.x);
        const uint gb5 = *(const uint*)(hpc + (uint)b5.x);
        const uint gb6 = *(const uint*)(hpc + (uint)b6.x);
        const uint gb7 = *(const uint*)(hpc + (uint)b7.x);
        GFMA2(accA, a0, ga0) GFMA2(accA, a1, ga1) GFMA2(accA, a2, ga2) GFMA2(accA, a3, ga3)
        GFMA2(accA, a4, ga4) GFMA2(accA, a5, ga5) GFMA2(accA, a6, ga6) GFMA2(accA, a7, ga7)
        GFMA2(accB, b0, gb0) GFMA2(accB, b1, gb1) GFMA2(accB, b2, gb2) GFMA2(accB, b3, gb3)
        GFMA2(accB, b4, gb4) GFMA2(accB, b5, gb5) GFMA2(accB, b6, gb6) GFMA2(accB, b7, gb7)
        jA += 8;
        jB += 8;
    }
    drain_row(recs, hpc, jA, eA, accA);
    drain_row(recs, hpc, jB, eB, accB);

    // ---- phase 2: relu + bf16 pack -> swizzled LDS tile ----
    {
        const uint pA = (uint)relu_bf(f2bf(accA.x)) |
                        ((uint)relu_bf(f2bf(accA.y)) << 16);
        const uint pB = (uint)relu_bf(f2bf(accB.x)) |
                        ((uint)relu_bf(f2bf(accB.y)) << 16);
        const int rA = 2 * w, rB = 2 * w + 1;
        *(uint*)(agg + rA * 256 + ((lane * 4) ^ ((rA & 7) << 4))) = pA;
        *(uint*)(agg + rB * 256 + ((lane * 4) ^ ((rB & 7) << 4))) = pB;
    }
    __syncthreads();

    // ---- phase 3: out = relu(agg) + relu(agg) @ Wres + bres ----
    const int l16 = lane & 15;
    const int lk = lane >> 4;
    const int ct = w;                 // col tile 0..7
    const int aswz = (l16 & 7) << 4;

    float4v acc = (float4v)(0.0f);
#pragma unroll
    for (int ks = 0; ks < 4; ++ks) {
        const short8v af = *(const short8v*)(
            agg + l16 * 256 + ((ks * 64 + lk * 16) ^ aswz));
        const short8v bf = *(const short8v*)(
            wsm + (ct * 16 + l16) * 256 + ((ks * 64 + lk * 16) ^ aswz));
        acc = __builtin_amdgcn_mfma_f32_16x16x32_bf16(af, bf, acc, 0, 0, 0);
    }

    const int col = ct * 16 + l16;
    const float bb = bres[col];
#pragma unroll
    for (int i = 0; i < 4; ++i) {
        const int rl = lk * 4 + i;
        const ushort au = *(const ushort*)(
            agg + rl * 256 + ((col * 2) ^ ((rl & 7) << 4)));
        const long grow = (long)blockIdx.x * 16 + rl;
        Y[grow * D + col] = bf2f(au) + acc[i] + bb;
    }
}

extern "C" void kernel_launch(void* const* d_in, const int* in_sizes, int n_in,
                              void* d_out, int out_size, void* d_ws, size_t ws_size,
                              hipStream_t stream) {
    const float* x    = (const float*)d_in[0];
    const float* W    = (const float*)d_in[1];
    const float* b    = (const float*)d_in[2];
    const float* Wres = (const float*)d_in[3];
    const float* bres = (const float*)d_in[4];
    const float* ev   = (const float*)d_in[5];
    const int*   er   = (const int*)d_in[6];
    const int*   ec   = (const int*)d_in[7];

    float* out = (float*)d_out;

    const int n = in_sizes[0] / D;   // 100000
    const int e = in_sizes[5];       // 1600000

    // ---- workspace layout ----
    char* ws = (char*)d_ws;
    size_t off_b = 0;
    auto alloc = [&](size_t bytes) {
        void* p = ws + off_b;
        off_b += (bytes + 511) & ~size_t(511);
        return p;
    };
    ushort* hb     = (ushort*)alloc((size_t)n * D * sizeof(ushort));        // 25.6 MB
    int2*   recs   = (int2*)alloc((size_t)NCH * CAP * sizeof(int2));        // 19.2 MB
    int*    rowptr = (int*)alloc((size_t)NCH * (RCH + 1) * sizeof(int));    // 403 KB
    ushort* Wt     = (ushort*)alloc((size_t)D * D * sizeof(ushort));
    ushort* Wtres  = (ushort*)alloc((size_t)D * D * sizeof(ushort));
    int2*   tmp    = (int2*)alloc((size_t)NB_S * CH_S * sizeof(int2));      // 12.8 MB
    int*    offs2  = (int*)alloc((size_t)NB_S * OS2 * sizeof(int));         // 1.6 MB
    (void)ws_size;

    // K0: weight transpose+cast (tiny, removes prep->gemm race in kA)
    k0_prep<<<PB, 256, 0, stream>>>(W, Wres, Wt, Wtres);

    // KA: scatter (latency-bound) || gemm0 h = x@W+b (BW-bound)
    kA_scatter_gemm<<<NB_S + GB64, 256, 0, stream>>>(ev, er, ec, offs2, tmp, e,
                                                     x, Wt, b, hb, n);

    // KB: per-chunk gather+sort -> recs/rowptr
    kB_sort<<<NCH, 256, 0, stream>>>(tmp, offs2, recs, rowptr);

    // K56: fused gather-aggregate + residual GEMM (round-9 best config)
    k56_spmm_gemm1<<<(n + 15) / 16, 512, 0, stream>>>(hb, recs, rowptr,
                                                      Wtres, bres, out, n);
}